// Round 2
// baseline (956.571 us; speedup 1.0000x reference)
//
#include <hip/hip_runtime.h>
#include <cstdio>

// ---------------------------------------------------------------------------
// BiLSTM  B=64, T=512, D=256, H=256
//   P0: bias vectors; quantize Whh to int8 (wq4[d][kc][j][gate] packed dwords)
//   P1: MFMA bf16 GEMM (fp32 in, converts while staging):
//       xproj[d][b*512+t][j*4+gate] = sum_k x[b,t,k]*Wih_d[n,k] + bias_d[n]
//   P2: recurrence: 128 WGs (64 batch x 2 dir) x 256 thr. Thread j owns all
//       4 gate rows (i,f,g,o) of hidden unit j: 256 int-dwords of int8
//       weights in VGPRs (__launch_bounds__(256,1) -> 512 VGPR cap).
//       h int8 in double-buffered LDS, ONE barrier/step, c in register.
// ---------------------------------------------------------------------------

typedef unsigned short ushort_t;
typedef __attribute__((ext_vector_type(8))) short short8;
typedef __attribute__((ext_vector_type(4))) float f32x4;

__device__ __forceinline__ ushort_t f2bf(float f) {
    union { float f; unsigned u; } v; v.f = f;
    unsigned r = v.u + 0x7fffu + ((v.u >> 16) & 1u);
    return (ushort_t)(r >> 16);
}
__device__ __forceinline__ float bf2f(ushort_t h) {
    union { unsigned u; float f; } v; v.u = ((unsigned)h) << 16;
    return v.f;
}

__device__ __forceinline__ float fexp2(float x) {
#if __has_builtin(__builtin_amdgcn_exp2f)
    return __builtin_amdgcn_exp2f(x);
#else
    return exp2f(x);
#endif
}
__device__ __forceinline__ float frcp(float x) {
#if __has_builtin(__builtin_amdgcn_rcpf)
    return __builtin_amdgcn_rcpf(x);
#else
    return 1.0f / x;
#endif
}
__device__ __forceinline__ float fsig(float x) {
    return frcp(1.0f + fexp2(-1.44269504089f * x));
}
__device__ __forceinline__ float ftanh(float x) {
    float e = fexp2(2.88539008178f * x);
    return 1.0f - 2.0f * frcp(e + 1.0f);
}

__device__ __forceinline__ int dot4(int a, int b, int c) {
#if __has_builtin(__builtin_amdgcn_sdot4)
    return __builtin_amdgcn_sdot4(a, b, c, false);
#else
    int r = c;
    r += ((a << 24) >> 24) * ((b << 24) >> 24);
    r += ((a << 16) >> 24) * ((b << 16) >> 24);
    r += ((a << 8) >> 24) * ((b << 8) >> 24);
    r += (a >> 24) * (b >> 24);
    return r;
#endif
}

// ---------------------------------------------------------------------------
// P0a: bias vectors biasv[d][n] = bih_d[n] + bhh_d[n]
__global__ __launch_bounds__(256) void k_bias(const float* __restrict__ bihf,
                                              const float* __restrict__ bhhf,
                                              const float* __restrict__ bihb,
                                              const float* __restrict__ bhhb,
                                              float* __restrict__ bv) {
    int i = blockIdx.x * 256 + threadIdx.x;
    if (i < 1024) bv[i] = bihf[i] + bhhf[i];
    else if (i < 2048) bv[i] = bihb[i - 1024] + bhhb[i - 1024];
}

// P0b: quantize Whh rows to int8.
// wq4[d*65536 + kc*1024 + j*4 + gate], kc=k/4, j=row&255, gate=row>>8.
// fscale4[d*1024 + j*4 + gate] = rowmax/(127*127).
__global__ __launch_bounds__(256) void k_quant(const float* __restrict__ whhf,
                                               const float* __restrict__ whhb,
                                               int* __restrict__ wq4,
                                               float* __restrict__ fscale4) {
    int rowg = blockIdx.x * 4 + (threadIdx.x >> 6);   // 0..2047
    int l = threadIdx.x & 63;                          // = kc
    int d = rowg >> 10;
    int row = rowg & 1023;
    const float* W = (d ? whhb : whhf) + (size_t)row * 256;
    float4 v = *(const float4*)&W[l * 4];
    float m = fmaxf(fmaxf(fabsf(v.x), fabsf(v.y)), fmaxf(fabsf(v.z), fabsf(v.w)));
    #pragma unroll
    for (int off = 32; off > 0; off >>= 1) m = fmaxf(m, __shfl_xor(m, off));
    float inv = (m > 0.0f) ? (127.0f / m) : 0.0f;
    int q0 = __float2int_rn(v.x * inv);
    int q1 = __float2int_rn(v.y * inv);
    int q2 = __float2int_rn(v.z * inv);
    int q3 = __float2int_rn(v.w * inv);
    q0 = min(127, max(-127, q0)); q1 = min(127, max(-127, q1));
    q2 = min(127, max(-127, q2)); q3 = min(127, max(-127, q3));
    int packed = (q0 & 255) | ((q1 & 255) << 8) | ((q2 & 255) << 16) | ((q3 & 255) << 24);
    int j = row & 255, gate = row >> 8;
    wq4[d * 65536 + l * 1024 + j * 4 + gate] = packed;
    if (l == 0) fscale4[d * 1024 + j * 4 + gate] = m / (127.0f * 127.0f);
}

// ---------------------------------------------------------------------------
// P1: bf16 GEMM from fp32 inputs. 128x128 tile, BK=32, 256 thr, mfma 16x16x32.
// Writes C[m, (n&255)*4 + (n>>8)] = f2bf(acc + bias[n]).
#define LDSOFF(r, kc) ((r) * 32 + ((((kc) + ((r) >> 1)) & 3) * 8))

__device__ __forceinline__ short8 pack8(float4 a, float4 b) {
    short8 r;
    r[0] = (short)f2bf(a.x); r[1] = (short)f2bf(a.y);
    r[2] = (short)f2bf(a.z); r[3] = (short)f2bf(a.w);
    r[4] = (short)f2bf(b.x); r[5] = (short)f2bf(b.y);
    r[6] = (short)f2bf(b.z); r[7] = (short)f2bf(b.w);
    return r;
}

__global__ __launch_bounds__(256) void k_gemm(const float* __restrict__ A,
                                              const float* __restrict__ Bf,
                                              const float* __restrict__ Bb,
                                              const float* __restrict__ biasv,
                                              ushort_t* __restrict__ Xp) {
    const int dir = blockIdx.z;
    const float* Bmat = dir ? Bb : Bf;
    const float* bv = biasv + dir * 1024;
    ushort_t* C = Xp + (size_t)dir * 33554432;
    const int tn = blockIdx.x;   // 0..7
    const int tm = blockIdx.y;   // 0..255
    const int tid = threadIdx.x;
    const int w = tid >> 6, l = tid & 63;
    const int wm = w & 1, wn = w >> 1;

    __shared__ ushort_t As[128 * 32];
    __shared__ ushort_t Bs[128 * 32];

    f32x4 acc[4][4];
    #pragma unroll
    for (int i = 0; i < 4; i++)
        #pragma unroll
        for (int jj = 0; jj < 4; jj++) acc[i][jj] = (f32x4){0.f, 0.f, 0.f, 0.f};

    const int r = tid >> 1, seg = tid & 1;   // 16 floats per thread per tile

    for (int kb = 0; kb < 8; kb++) {
        __syncthreads();
        {
            const float* pa = &A[(size_t)(tm * 128 + r) * 256 + kb * 32 + seg * 16];
            float4 a0 = *(const float4*)&pa[0];
            float4 a1 = *(const float4*)&pa[4];
            float4 a2 = *(const float4*)&pa[8];
            float4 a3 = *(const float4*)&pa[12];
            const float* pb = &Bmat[(size_t)(tn * 128 + r) * 256 + kb * 32 + seg * 16];
            float4 b0 = *(const float4*)&pb[0];
            float4 b1 = *(const float4*)&pb[4];
            float4 b2 = *(const float4*)&pb[8];
            float4 b3 = *(const float4*)&pb[12];
            *(short8*)&As[LDSOFF(r, seg * 2)]     = pack8(a0, a1);
            *(short8*)&As[LDSOFF(r, seg * 2 + 1)] = pack8(a2, a3);
            *(short8*)&Bs[LDSOFF(r, seg * 2)]     = pack8(b0, b1);
            *(short8*)&Bs[LDSOFF(r, seg * 2 + 1)] = pack8(b2, b3);
        }
        __syncthreads();
        short8 af[4], bfr[4];
        const int q = l >> 4;
        #pragma unroll
        for (int mt = 0; mt < 4; mt++) {
            int rr = wm * 64 + mt * 16 + (l & 15);
            af[mt] = *(const short8*)&As[LDSOFF(rr, q)];
        }
        #pragma unroll
        for (int nt = 0; nt < 4; nt++) {
            int rr = wn * 64 + nt * 16 + (l & 15);
            bfr[nt] = *(const short8*)&Bs[LDSOFF(rr, q)];
        }
        #pragma unroll
        for (int mt = 0; mt < 4; mt++)
            #pragma unroll
            for (int nt = 0; nt < 4; nt++)
                acc[mt][nt] = __builtin_amdgcn_mfma_f32_16x16x32_bf16(
                    af[mt], bfr[nt], acc[mt][nt], 0, 0, 0);
    }
    // epilogue: C/D layout col = lane&15 (n), row = (lane>>4)*4 + reg (m)
    #pragma unroll
    for (int nt = 0; nt < 4; nt++) {
        int n = tn * 128 + wn * 64 + nt * 16 + (l & 15);
        float bn = bv[n];
        int cperm = (n & 255) * 4 + (n >> 8);
        #pragma unroll
        for (int mt = 0; mt < 4; mt++) {
            #pragma unroll
            for (int rr = 0; rr < 4; rr++) {
                int m = tm * 128 + wm * 64 + mt * 16 + (l >> 4) * 4 + rr;
                C[(size_t)m * 1024 + cperm] = f2bf(acc[mt][nt][rr] + bn);
            }
        }
    }
}

// ---------------------------------------------------------------------------
// P2: recurrence. grid (64 batch, 2 dir) x 256 threads.
__device__ __forceinline__ int time_idx(int s, int len, int d) {
    int sc = (s < len - 1) ? s : (len - 1);
    return (d == 0) ? sc : (len - 1 - sc);
}

__global__ __launch_bounds__(256, 1) void k_rec(const ushort_t* __restrict__ xproj,
                                                const int* __restrict__ wq4,
                                                const float* __restrict__ fscale4,
                                                const int* __restrict__ lens,
                                                float* __restrict__ out) {
    const int b = blockIdx.x, d = blockIdx.y;
    const int j = threadIdx.x;
    int len = lens[b];
    if (len < 1) len = 1;
    if (len > 512) len = 512;
    const ushort_t* xp = xproj + ((size_t)d * 64 + b) * 524288;  // 512*1024
    const int* wq = wq4 + d * 65536;
    float4 fr = *(const float4*)&fscale4[d * 1024 + j * 4];  // i,f,g,o

    int w0[64], w1[64], w2[64], w3[64];
    #pragma unroll
    for (int kc = 0; kc < 64; kc++) {
        int4 v = *(const int4*)&wq[kc * 1024 + j * 4];
        w0[kc] = v.x; w1[kc] = v.y; w2[kc] = v.z; w3[kc] = v.w;
    }

    __shared__ int h8[2][64] __attribute__((aligned(16)));
    if (j < 64) { h8[0][j] = 0; }

    // zero-fill this direction's half for t in [len, 512)
    {
        float4 z = {0.f, 0.f, 0.f, 0.f};
        int total4 = (512 - len) * 64;
        for (int i = j; i < total4; i += 256) {
            int t = len + (i >> 6);
            int c4 = i & 63;
            *(float4*)&out[((size_t)b * 512 + t) * 512 + d * 256 + c4 * 4] = z;
        }
    }
    __syncthreads();

    float c_state = 0.0f;
    uint2 xv0 = *(const uint2*)&xp[(size_t)time_idx(0, len, d) * 1024 + j * 4];
    uint2 xv1 = *(const uint2*)&xp[(size_t)time_idx(1, len, d) * 1024 + j * 4];

    for (int s = 0; s < len; s++) {
        uint2 xc = xv0;
        xv0 = xv1;
        uint2 xn = *(const uint2*)&xp[(size_t)time_idx(s + 2, len, d) * 1024 + j * 4];

        const int4* hb = (const int4*)&h8[s & 1][0];
        int a0 = 0, c0 = 0, a1 = 0, c1 = 0, a2 = 0, c2 = 0, a3 = 0, c3 = 0;
        #pragma unroll
        for (int kc = 0; kc < 16; kc++) {
            int4 hv = hb[kc];   // wave-uniform -> LDS broadcast
            a0 = dot4(w0[kc * 4 + 0], hv.x, a0); c0 = dot4(w0[kc * 4 + 1], hv.y, c0);
            a0 = dot4(w0[kc * 4 + 2], hv.z, a0); c0 = dot4(w0[kc * 4 + 3], hv.w, c0);
            a1 = dot4(w1[kc * 4 + 0], hv.x, a1); c1 = dot4(w1[kc * 4 + 1], hv.y, c1);
            a1 = dot4(w1[kc * 4 + 2], hv.z, a1); c1 = dot4(w1[kc * 4 + 3], hv.w, c1);
            a2 = dot4(w2[kc * 4 + 0], hv.x, a2); c2 = dot4(w2[kc * 4 + 1], hv.y, c2);
            a2 = dot4(w2[kc * 4 + 2], hv.z, a2); c2 = dot4(w2[kc * 4 + 3], hv.w, c2);
            a3 = dot4(w3[kc * 4 + 0], hv.x, a3); c3 = dot4(w3[kc * 4 + 1], hv.y, c3);
            a3 = dot4(w3[kc * 4 + 2], hv.z, a3); c3 = dot4(w3[kc * 4 + 3], hv.w, c3);
        }
        float pi = bf2f((ushort_t)(xc.x & 0xffffu)) + fr.x * (float)(a0 + c0);
        float pf = bf2f((ushort_t)(xc.x >> 16))     + fr.y * (float)(a1 + c1);
        float pg = bf2f((ushort_t)(xc.y & 0xffffu)) + fr.z * (float)(a2 + c2);
        float po = bf2f((ushort_t)(xc.y >> 16))     + fr.w * (float)(a3 + c3);

        float ig = fsig(pi), fg = fsig(pf), gg = ftanh(pg), og = fsig(po);
        c_state = fg * c_state + ig * gg;
        float h = og * ftanh(c_state);

        int t = time_idx(s, len, d);
        out[((size_t)b * 512 + t) * 512 + d * 256 + j] = h;

        int q = __float2int_rn(h * 127.0f);
        q = min(127, max(-127, q));
        ((char*)&h8[1 - (s & 1)][0])[j] = (char)q;

        xv1 = xn;
        __syncthreads();
    }
}

// ---------------------------------------------------------------------------
extern "C" void kernel_launch(void* const* d_in, const int* in_sizes, int n_in,
                              void* d_out, int out_size, void* d_ws, size_t ws_size,
                              hipStream_t stream) {
    (void)in_sizes; (void)n_in; (void)out_size;
    const float* x    = (const float*)d_in[0];
    const int*   lens = (const int*)d_in[1];
    const float* wihf = (const float*)d_in[2];
    const float* whhf = (const float*)d_in[3];
    const float* bihf = (const float*)d_in[4];
    const float* bhhf = (const float*)d_in[5];
    const float* wihb = (const float*)d_in[6];
    const float* whhb = (const float*)d_in[7];
    const float* bihb = (const float*)d_in[8];
    const float* bhhb = (const float*)d_in[9];
    float* out = (float*)d_out;

    char* ws = (char*)d_ws;
    float* biasv    = (float*)(ws + 0);          //      8,192 B
    int*   wq4      = (int*)(ws + 8192);         //    524,288 B
    float* fscale4  = (float*)(ws + 532480);     //      8,192 B
    ushort_t* xproj = (ushort_t*)(ws + 540672);  // 134,217,728 B
    const size_t REQ = 540672 + 134217728ull;
    if (ws_size < REQ) {
        fprintf(stderr, "kernel_launch: ws too small: %zu < %zu\n", ws_size, REQ);
    }

    k_bias<<<8, 256, 0, stream>>>(bihf, bhhf, bihb, bhhb, biasv);
    k_quant<<<512, 256, 0, stream>>>(whhf, whhb, wq4, fscale4);
    k_gemm<<<dim3(8, 256, 2), 256, 0, stream>>>(x, wihf, wihb, biasv, xproj);
    k_rec<<<dim3(64, 2), 256, 0, stream>>>(xproj, wq4, fscale4, lens, out);
}

// Round 3
// 926.358 us; speedup vs baseline: 1.0326x; 1.0326x over previous
//
#include <hip/hip_runtime.h>
#include <cstdio>

// ---------------------------------------------------------------------------
// BiLSTM  B=64, T=512, D=256, H=256
//   P0: convert x, Wih to bf16; bias vectors; quantize Whh to int8
//   P1: MFMA bf16 GEMM -> xproj[d][b*512+t][j*4+gate] (bf16)
//   P2: recurrence: 128 WGs (64 batch x 2 dir) x 256 thr. Thread j owns all
//       4 gate rows of hidden unit j as ext_vector int8 weights (256 dwords,
//       SSA values -> guaranteed VGPR residency, no alloca). h int8 in
//       double-buffered LDS; per-step barrier is raw lgkm-only
//       s_waitcnt+s_barrier so global stores/prefetches stay in flight.
// ---------------------------------------------------------------------------

typedef unsigned short ushort_t;
typedef __attribute__((ext_vector_type(8))) short short8;
typedef __attribute__((ext_vector_type(4))) float f32x4;
typedef __attribute__((ext_vector_type(64))) int i32x64;

__device__ __forceinline__ ushort_t f2bf(float f) {
    union { float f; unsigned u; } v; v.f = f;
    unsigned r = v.u + 0x7fffu + ((v.u >> 16) & 1u);
    return (ushort_t)(r >> 16);
}
__device__ __forceinline__ float bf2f(ushort_t h) {
    union { unsigned u; float f; } v; v.u = ((unsigned)h) << 16;
    return v.f;
}

__device__ __forceinline__ float fexp2(float x) {
#if __has_builtin(__builtin_amdgcn_exp2f)
    return __builtin_amdgcn_exp2f(x);
#else
    return exp2f(x);
#endif
}
__device__ __forceinline__ float frcp(float x) {
#if __has_builtin(__builtin_amdgcn_rcpf)
    return __builtin_amdgcn_rcpf(x);
#else
    return 1.0f / x;
#endif
}
__device__ __forceinline__ float fsig(float x) {
    return frcp(1.0f + fexp2(-1.44269504089f * x));
}
__device__ __forceinline__ float ftanh(float x) {
    float e = fexp2(2.88539008178f * x);
    return 1.0f - 2.0f * frcp(e + 1.0f);
}

__device__ __forceinline__ int dot4(int a, int b, int c) {
#if __has_builtin(__builtin_amdgcn_sdot4)
    return __builtin_amdgcn_sdot4(a, b, c, false);
#else
    int r = c;
    r += ((a << 24) >> 24) * ((b << 24) >> 24);
    r += ((a << 16) >> 24) * ((b << 16) >> 24);
    r += ((a << 8) >> 24) * ((b << 8) >> 24);
    r += (a >> 24) * (b >> 24);
    return r;
#endif
}

// LDS-only barrier: drain lgkm (LDS writes) but NOT vmcnt, so global
// stores / prefetch loads stay in flight across steps.
__device__ __forceinline__ void lds_barrier() {
    asm volatile("s_waitcnt lgkmcnt(0)\n\ts_barrier" ::: "memory");
}

// ---------------------------------------------------------------------------
// P0a: fp32 -> bf16 (n multiple of 4)
__global__ __launch_bounds__(256) void k_f2bf(const float* __restrict__ in,
                                              ushort_t* __restrict__ out, int n) {
    int i = (blockIdx.x * 256 + threadIdx.x) * 4;
    if (i + 3 < n) {
        float4 v = *(const float4*)&in[i];
        ushort4 o;
        o.x = f2bf(v.x); o.y = f2bf(v.y); o.z = f2bf(v.z); o.w = f2bf(v.w);
        *(ushort4*)&out[i] = o;
    }
}

// P0b: bias vectors biasv[d][n] = bih_d[n] + bhh_d[n]
__global__ __launch_bounds__(256) void k_bias(const float* __restrict__ bihf,
                                              const float* __restrict__ bhhf,
                                              const float* __restrict__ bihb,
                                              const float* __restrict__ bhhb,
                                              float* __restrict__ bv) {
    int i = blockIdx.x * 256 + threadIdx.x;
    if (i < 1024) bv[i] = bihf[i] + bhhf[i];
    else if (i < 2048) bv[i] = bihb[i - 1024] + bhhb[i - 1024];
}

// P0c: quantize Whh rows to int8.
// wq4[d*65536 + kc*1024 + j*4 + gate], kc=k/4, j=row&255, gate=row>>8.
// fscale4[d*1024 + j*4 + gate] = rowmax/(127*127).
__global__ __launch_bounds__(256) void k_quant(const float* __restrict__ whhf,
                                               const float* __restrict__ whhb,
                                               int* __restrict__ wq4,
                                               float* __restrict__ fscale4) {
    int rowg = blockIdx.x * 4 + (threadIdx.x >> 6);   // 0..2047
    int l = threadIdx.x & 63;                          // = kc
    int d = rowg >> 10;
    int row = rowg & 1023;
    const float* W = (d ? whhb : whhf) + (size_t)row * 256;
    float4 v = *(const float4*)&W[l * 4];
    float m = fmaxf(fmaxf(fabsf(v.x), fabsf(v.y)), fmaxf(fabsf(v.z), fabsf(v.w)));
    #pragma unroll
    for (int off = 32; off > 0; off >>= 1) m = fmaxf(m, __shfl_xor(m, off));
    float inv = (m > 0.0f) ? (127.0f / m) : 0.0f;
    int q0 = __float2int_rn(v.x * inv);
    int q1 = __float2int_rn(v.y * inv);
    int q2 = __float2int_rn(v.z * inv);
    int q3 = __float2int_rn(v.w * inv);
    q0 = min(127, max(-127, q0)); q1 = min(127, max(-127, q1));
    q2 = min(127, max(-127, q2)); q3 = min(127, max(-127, q3));
    int packed = (q0 & 255) | ((q1 & 255) << 8) | ((q2 & 255) << 16) | ((q3 & 255) << 24);
    int j = row & 255, gate = row >> 8;
    wq4[d * 65536 + l * 1024 + j * 4 + gate] = packed;
    if (l == 0) fscale4[d * 1024 + j * 4 + gate] = m / (127.0f * 127.0f);
}

// ---------------------------------------------------------------------------
// P1: bf16 GEMM (R1 structure). C[m, (n&255)*4 + (n>>8)] = acc + bias[n].
// 128x128 tile, BK=32, 256 threads (2x2 waves of 64x64), mfma 16x16x32.
#define LDSOFF(r, kc) ((r) * 32 + ((((kc) + ((r) >> 1)) & 3) * 8))

__global__ __launch_bounds__(256) void k_gemm(const ushort_t* __restrict__ A,
                                              const ushort_t* __restrict__ Bw,
                                              const float* __restrict__ biasv,
                                              ushort_t* __restrict__ Xp) {
    const int dir = blockIdx.z;
    const ushort_t* Bmat = Bw + dir * 262144;
    const float* bv = biasv + dir * 1024;
    ushort_t* C = Xp + (size_t)dir * 33554432;
    const int tn = blockIdx.x;   // 0..7
    const int tm = blockIdx.y;   // 0..255
    const int tid = threadIdx.x;
    const int w = tid >> 6, l = tid & 63;
    const int wm = w & 1, wn = w >> 1;

    __shared__ ushort_t As[128 * 32];
    __shared__ ushort_t Bs[128 * 32];

    f32x4 acc[4][4];
    #pragma unroll
    for (int i = 0; i < 4; i++)
        #pragma unroll
        for (int jj = 0; jj < 4; jj++) acc[i][jj] = (f32x4){0.f, 0.f, 0.f, 0.f};

    const int r0 = tid >> 2, c0 = tid & 3;            // chunk 0: rows 0..63
    const int r1 = (tid + 256) >> 2, c1 = tid & 3;    // chunk 1: rows 64..127

    for (int kb = 0; kb < 8; kb++) {
        __syncthreads();
        {
            short8 a0 = *(const short8*)&A[((size_t)(tm * 128 + r0)) * 256 + kb * 32 + c0 * 8];
            short8 a1 = *(const short8*)&A[((size_t)(tm * 128 + r1)) * 256 + kb * 32 + c1 * 8];
            short8 b0 = *(const short8*)&Bmat[((size_t)(tn * 128 + r0)) * 256 + kb * 32 + c0 * 8];
            short8 b1 = *(const short8*)&Bmat[((size_t)(tn * 128 + r1)) * 256 + kb * 32 + c1 * 8];
            *(short8*)&As[LDSOFF(r0, c0)] = a0;
            *(short8*)&As[LDSOFF(r1, c1)] = a1;
            *(short8*)&Bs[LDSOFF(r0, c0)] = b0;
            *(short8*)&Bs[LDSOFF(r1, c1)] = b1;
        }
        __syncthreads();
        short8 af[4], bfr[4];
        const int q = l >> 4;
        #pragma unroll
        for (int mt = 0; mt < 4; mt++) {
            int rr = wm * 64 + mt * 16 + (l & 15);
            af[mt] = *(const short8*)&As[LDSOFF(rr, q)];
        }
        #pragma unroll
        for (int nt = 0; nt < 4; nt++) {
            int rr = wn * 64 + nt * 16 + (l & 15);
            bfr[nt] = *(const short8*)&Bs[LDSOFF(rr, q)];
        }
        #pragma unroll
        for (int mt = 0; mt < 4; mt++)
            #pragma unroll
            for (int nt = 0; nt < 4; nt++)
                acc[mt][nt] = __builtin_amdgcn_mfma_f32_16x16x32_bf16(
                    af[mt], bfr[nt], acc[mt][nt], 0, 0, 0);
    }
    // epilogue: C/D layout col = lane&15 (n), row = (lane>>4)*4 + reg (m);
    // permute column to (n&255)*4 + (n>>8) for the recurrent kernel.
    #pragma unroll
    for (int nt = 0; nt < 4; nt++) {
        int n = tn * 128 + wn * 64 + nt * 16 + (l & 15);
        float bn = bv[n];
        int cperm = (n & 255) * 4 + (n >> 8);
        #pragma unroll
        for (int mt = 0; mt < 4; mt++) {
            #pragma unroll
            for (int rr = 0; rr < 4; rr++) {
                int m = tm * 128 + wm * 64 + mt * 16 + (l >> 4) * 4 + rr;
                C[(size_t)m * 1024 + cperm] = f2bf(acc[mt][nt][rr] + bn);
            }
        }
    }
}

// ---------------------------------------------------------------------------
// P2: recurrence. grid (64 batch, 2 dir) x 256 threads.
__device__ __forceinline__ int time_idx(int s, int len, int d) {
    int sc = (s < len - 1) ? s : (len - 1);
    return (d == 0) ? sc : (len - 1 - sc);
}

__global__ __launch_bounds__(256, 1) void k_rec(const ushort_t* __restrict__ xproj,
                                                const int* __restrict__ wq4,
                                                const float* __restrict__ fscale4,
                                                const int* __restrict__ lens,
                                                float* __restrict__ out) {
    const int b = blockIdx.x, d = blockIdx.y;
    const int j = threadIdx.x;
    int len = lens[b];
    if (len < 1) len = 1;
    if (len > 512) len = 512;
    const ushort_t* xp = xproj + ((size_t)d * 64 + b) * 524288;  // 512*1024
    const int* wq = wq4 + d * 65536;
    float4 fr = *(const float4*)&fscale4[d * 1024 + j * 4];  // i,f,g,o

    // 256 dwords of int8 weights as SSA vectors -> VGPRs (no alloca).
    i32x64 w0, w1, w2, w3;
    #pragma unroll
    for (int kc = 0; kc < 64; kc++) {
        int4 v = *(const int4*)&wq[kc * 1024 + j * 4];
        w0[kc] = v.x; w1[kc] = v.y; w2[kc] = v.z; w3[kc] = v.w;
    }

    __shared__ int h8[2][64] __attribute__((aligned(16)));
    if (j < 64) { h8[0][j] = 0; }

    // zero-fill this direction's half for t in [len, 512)
    {
        float4 z = {0.f, 0.f, 0.f, 0.f};
        int total4 = (512 - len) * 64;
        for (int i = j; i < total4; i += 256) {
            int t = len + (i >> 6);
            int c4 = i & 63;
            *(float4*)&out[((size_t)b * 512 + t) * 512 + d * 256 + c4 * 4] = z;
        }
    }
    __syncthreads();

    float c_state = 0.0f;
    uint2 xv0 = *(const uint2*)&xp[(size_t)time_idx(0, len, d) * 1024 + j * 4];
    uint2 xv1 = *(const uint2*)&xp[(size_t)time_idx(1, len, d) * 1024 + j * 4];

    for (int s = 0; s < len; s++) {
        uint2 xc = xv0;
        xv0 = xv1;
        uint2 xn = *(const uint2*)&xp[(size_t)time_idx(s + 2, len, d) * 1024 + j * 4];

        const int4* hb = (const int4*)&h8[s & 1][0];
        int a0 = 0, c0 = 0, a1 = 0, c1 = 0, a2 = 0, c2 = 0, a3 = 0, c3 = 0;
        #pragma unroll
        for (int kc = 0; kc < 16; kc++) {
            int4 hv = hb[kc];   // wave-uniform -> LDS broadcast
            a0 = dot4(w0[kc * 4 + 0], hv.x, a0); c0 = dot4(w0[kc * 4 + 1], hv.y, c0);
            a0 = dot4(w0[kc * 4 + 2], hv.z, a0); c0 = dot4(w0[kc * 4 + 3], hv.w, c0);
            a1 = dot4(w1[kc * 4 + 0], hv.x, a1); c1 = dot4(w1[kc * 4 + 1], hv.y, c1);
            a1 = dot4(w1[kc * 4 + 2], hv.z, a1); c1 = dot4(w1[kc * 4 + 3], hv.w, c1);
            a2 = dot4(w2[kc * 4 + 0], hv.x, a2); c2 = dot4(w2[kc * 4 + 1], hv.y, c2);
            a2 = dot4(w2[kc * 4 + 2], hv.z, a2); c2 = dot4(w2[kc * 4 + 3], hv.w, c2);
            a3 = dot4(w3[kc * 4 + 0], hv.x, a3); c3 = dot4(w3[kc * 4 + 1], hv.y, c3);
            a3 = dot4(w3[kc * 4 + 2], hv.z, a3); c3 = dot4(w3[kc * 4 + 3], hv.w, c3);
        }
        float pi = bf2f((ushort_t)(xc.x & 0xffffu)) + fr.x * (float)(a0 + c0);
        float pf = bf2f((ushort_t)(xc.x >> 16))     + fr.y * (float)(a1 + c1);
        float pg = bf2f((ushort_t)(xc.y & 0xffffu)) + fr.z * (float)(a2 + c2);
        float po = bf2f((ushort_t)(xc.y >> 16))     + fr.w * (float)(a3 + c3);

        float ig = fsig(pi), fg = fsig(pf), gg = ftanh(pg), og = fsig(po);
        c_state = fg * c_state + ig * gg;
        float h = og * ftanh(c_state);

        int t = time_idx(s, len, d);
        out[((size_t)b * 512 + t) * 512 + d * 256 + j] = h;

        int q = __float2int_rn(h * 127.0f);
        q = min(127, max(-127, q));
        ((char*)&h8[1 - (s & 1)][0])[j] = (char)q;

        xv1 = xn;
        lds_barrier();  // lgkm-only: stores/prefetches stay in flight
    }
}

// ---------------------------------------------------------------------------
extern "C" void kernel_launch(void* const* d_in, const int* in_sizes, int n_in,
                              void* d_out, int out_size, void* d_ws, size_t ws_size,
                              hipStream_t stream) {
    (void)in_sizes; (void)n_in; (void)out_size;
    const float* x    = (const float*)d_in[0];
    const int*   lens = (const int*)d_in[1];
    const float* wihf = (const float*)d_in[2];
    const float* whhf = (const float*)d_in[3];
    const float* bihf = (const float*)d_in[4];
    const float* bhhf = (const float*)d_in[5];
    const float* wihb = (const float*)d_in[6];
    const float* whhb = (const float*)d_in[7];
    const float* bihb = (const float*)d_in[8];
    const float* bhhb = (const float*)d_in[9];
    float* out = (float*)d_out;

    char* ws = (char*)d_ws;
    ushort_t* xbf    = (ushort_t*)(ws + 0);          //  16,777,216 B
    ushort_t* wihbf  = (ushort_t*)(ws + 16777216);   //   1,048,576 B
    float*    biasv  = (float*)(ws + 17825792);      //       8,192 B
    int*      wq4    = (int*)(ws + 17833984);        //     524,288 B
    float*    fscale4= (float*)(ws + 18358272);      //       8,192 B
    ushort_t* xproj  = (ushort_t*)(ws + 18366464);   // 134,217,728 B
    const size_t REQ = 18366464 + 134217728ull;
    if (ws_size < REQ) {
        fprintf(stderr, "kernel_launch: ws too small: %zu < %zu\n", ws_size, REQ);
    }

    k_f2bf<<<8192, 256, 0, stream>>>(x, xbf, 8388608);
    k_f2bf<<<256, 256, 0, stream>>>(wihf, wihbf, 262144);
    k_f2bf<<<256, 256, 0, stream>>>(wihb, wihbf + 262144, 262144);
    k_bias<<<8, 256, 0, stream>>>(bihf, bhhf, bihb, bhhb, biasv);
    k_quant<<<512, 256, 0, stream>>>(whhf, whhb, wq4, fscale4);
    k_gemm<<<dim3(8, 256, 2), 256, 0, stream>>>(xbf, wihbf, biasv, xproj);
    k_rec<<<dim3(64, 2), 256, 0, stream>>>(xproj, wq4, fscale4, lens, out);
}

// Round 4
// 860.327 us; speedup vs baseline: 1.1119x; 1.0768x over previous
//
#include <hip/hip_runtime.h>
#include <cstdio>

// ---------------------------------------------------------------------------
// BiLSTM  B=64, T=512, D=256, H=256
//   P0: x -> bf16; Wih -> bf16 with gate-permuted rows (n -> (n&255)*4+(n>>8));
//       permuted bias vectors; Whh -> int8 wq4[d][kc][j][gate]
//   P1: MFMA bf16 GEMM (contiguous epilogue) -> xproj[d][b*512+t][j*4+gate]
//   P2: recurrence: 128 WGs (64 batch x 2 dir) x 256 thr. Thread j owns all
//       4 gate rows of hidden unit j: 256 int8-packed dwords pinned into
//       VGPRs via volatile asm ties (compiler cannot sink/remat the loads
//       into the time loop). h int8 in double-buffered LDS; per-step barrier
//       is lgkm-only s_waitcnt+s_barrier so global traffic stays in flight.
// ---------------------------------------------------------------------------

typedef unsigned short ushort_t;
typedef __attribute__((ext_vector_type(8))) short short8;
typedef __attribute__((ext_vector_type(4))) float f32x4;

__device__ __forceinline__ ushort_t f2bf(float f) {
    union { float f; unsigned u; } v; v.f = f;
    unsigned r = v.u + 0x7fffu + ((v.u >> 16) & 1u);
    return (ushort_t)(r >> 16);
}
__device__ __forceinline__ float bf2f(ushort_t h) {
    union { unsigned u; float f; } v; v.u = ((unsigned)h) << 16;
    return v.f;
}

__device__ __forceinline__ float fexp2(float x) {
#if __has_builtin(__builtin_amdgcn_exp2f)
    return __builtin_amdgcn_exp2f(x);
#else
    return exp2f(x);
#endif
}
__device__ __forceinline__ float frcp(float x) {
#if __has_builtin(__builtin_amdgcn_rcpf)
    return __builtin_amdgcn_rcpf(x);
#else
    return 1.0f / x;
#endif
}
__device__ __forceinline__ float fsig(float x) {
    return frcp(1.0f + fexp2(-1.44269504089f * x));
}
__device__ __forceinline__ float ftanh(float x) {
    float e = fexp2(2.88539008178f * x);
    return 1.0f - 2.0f * frcp(e + 1.0f);
}

__device__ __forceinline__ int dot4(int a, int b, int c) {
#if __has_builtin(__builtin_amdgcn_sdot4)
    return __builtin_amdgcn_sdot4(a, b, c, false);
#else
    int r = c;
    r += ((a << 24) >> 24) * ((b << 24) >> 24);
    r += ((a << 16) >> 24) * ((b << 16) >> 24);
    r += ((a << 8) >> 24) * ((b << 8) >> 24);
    r += (a >> 24) * (b >> 24);
    return r;
#endif
}

// LDS-only barrier: drain lgkm (LDS ops) but NOT vmcnt.
__device__ __forceinline__ void lds_barrier() {
    asm volatile("s_waitcnt lgkmcnt(0)\n\ts_barrier" ::: "memory");
}

// ---------------------------------------------------------------------------
// P0a: fp32 -> bf16 (n multiple of 4)
__global__ __launch_bounds__(256) void k_f2bf(const float* __restrict__ in,
                                              ushort_t* __restrict__ out, int n) {
    int i = (blockIdx.x * 256 + threadIdx.x) * 4;
    if (i + 3 < n) {
        float4 v = *(const float4*)&in[i];
        ushort4 o;
        o.x = f2bf(v.x); o.y = f2bf(v.y); o.z = f2bf(v.z); o.w = f2bf(v.w);
        *(ushort4*)&out[i] = o;
    }
}

// P0b: Wih fp32 -> bf16 with gate-permuted ROW order:
//   dst[d][(n&255)*4 + (n>>8)][k] = src_d[n][k]
// one wave per row; lane l handles k = 4l..4l+3.
__global__ __launch_bounds__(256) void k_wih(const float* __restrict__ wihf,
                                             const float* __restrict__ wihb,
                                             ushort_t* __restrict__ dst) {
    int d = blockIdx.y;
    int n = blockIdx.x * 4 + (threadIdx.x >> 6);   // 0..1023
    int l = threadIdx.x & 63;
    const float* src = (d ? wihb : wihf) + (size_t)n * 256;
    float4 v = *(const float4*)&src[l * 4];
    int np = (n & 255) * 4 + (n >> 8);
    ushort4 o;
    o.x = f2bf(v.x); o.y = f2bf(v.y); o.z = f2bf(v.z); o.w = f2bf(v.w);
    *(ushort4*)&dst[((size_t)d * 1024 + np) * 256 + l * 4] = o;
}

// P0c: permuted bias vectors bv[d][(n&255)*4 + (n>>8)] = bih_d[n] + bhh_d[n]
__global__ __launch_bounds__(256) void k_bias(const float* __restrict__ bihf,
                                              const float* __restrict__ bhhf,
                                              const float* __restrict__ bihb,
                                              const float* __restrict__ bhhb,
                                              float* __restrict__ bv) {
    int i = blockIdx.x * 256 + threadIdx.x;   // 0..2047
    int d = i >> 10, n = i & 1023;
    float s = d ? (bihb[n] + bhhb[n]) : (bihf[n] + bhhf[n]);
    bv[d * 1024 + (n & 255) * 4 + (n >> 8)] = s;
}

// P0d: quantize Whh rows to int8.
// wq4[d*65536 + kc*1024 + j*4 + gate], kc=k/4, j=row&255, gate=row>>8.
// fscale4[d*1024 + j*4 + gate] = rowmax/(127*127).
__global__ __launch_bounds__(256) void k_quant(const float* __restrict__ whhf,
                                               const float* __restrict__ whhb,
                                               int* __restrict__ wq4,
                                               float* __restrict__ fscale4) {
    int rowg = blockIdx.x * 4 + (threadIdx.x >> 6);   // 0..2047
    int l = threadIdx.x & 63;                          // = kc
    int d = rowg >> 10;
    int row = rowg & 1023;
    const float* W = (d ? whhb : whhf) + (size_t)row * 256;
    float4 v = *(const float4*)&W[l * 4];
    float m = fmaxf(fmaxf(fabsf(v.x), fabsf(v.y)), fmaxf(fabsf(v.z), fabsf(v.w)));
    #pragma unroll
    for (int off = 32; off > 0; off >>= 1) m = fmaxf(m, __shfl_xor(m, off));
    float inv = (m > 0.0f) ? (127.0f / m) : 0.0f;
    int q0 = __float2int_rn(v.x * inv);
    int q1 = __float2int_rn(v.y * inv);
    int q2 = __float2int_rn(v.z * inv);
    int q3 = __float2int_rn(v.w * inv);
    q0 = min(127, max(-127, q0)); q1 = min(127, max(-127, q1));
    q2 = min(127, max(-127, q2)); q3 = min(127, max(-127, q3));
    int packed = (q0 & 255) | ((q1 & 255) << 8) | ((q2 & 255) << 16) | ((q3 & 255) << 24);
    int j = row & 255, gate = row >> 8;
    wq4[d * 65536 + l * 1024 + j * 4 + gate] = packed;
    if (l == 0) fscale4[d * 1024 + j * 4 + gate] = m / (127.0f * 127.0f);
}

// ---------------------------------------------------------------------------
// P1: bf16 GEMM (R1 structure, contiguous epilogue). B rows pre-permuted, so
// C[m][n] directly gives xproj[m][j*4+gate].
#define LDSOFF(r, kc) ((r) * 32 + ((((kc) + ((r) >> 1)) & 3) * 8))

__global__ __launch_bounds__(256) void k_gemm(const ushort_t* __restrict__ A,
                                              const ushort_t* __restrict__ Bw,
                                              const float* __restrict__ biasv,
                                              ushort_t* __restrict__ Xp) {
    const int dir = blockIdx.z;
    const ushort_t* Bmat = Bw + dir * 262144;
    const float* bv = biasv + dir * 1024;
    ushort_t* C = Xp + (size_t)dir * 33554432;
    const int tn = blockIdx.x;   // 0..7
    const int tm = blockIdx.y;   // 0..255
    const int tid = threadIdx.x;
    const int w = tid >> 6, l = tid & 63;
    const int wm = w & 1, wn = w >> 1;

    __shared__ ushort_t As[128 * 32];
    __shared__ ushort_t Bs[128 * 32];

    f32x4 acc[4][4];
    #pragma unroll
    for (int i = 0; i < 4; i++)
        #pragma unroll
        for (int jj = 0; jj < 4; jj++) acc[i][jj] = (f32x4){0.f, 0.f, 0.f, 0.f};

    const int r0 = tid >> 2, c0 = tid & 3;
    const int r1 = (tid + 256) >> 2, c1 = tid & 3;

    for (int kb = 0; kb < 8; kb++) {
        __syncthreads();
        {
            short8 a0 = *(const short8*)&A[((size_t)(tm * 128 + r0)) * 256 + kb * 32 + c0 * 8];
            short8 a1 = *(const short8*)&A[((size_t)(tm * 128 + r1)) * 256 + kb * 32 + c1 * 8];
            short8 b0 = *(const short8*)&Bmat[((size_t)(tn * 128 + r0)) * 256 + kb * 32 + c0 * 8];
            short8 b1 = *(const short8*)&Bmat[((size_t)(tn * 128 + r1)) * 256 + kb * 32 + c1 * 8];
            *(short8*)&As[LDSOFF(r0, c0)] = a0;
            *(short8*)&As[LDSOFF(r1, c1)] = a1;
            *(short8*)&Bs[LDSOFF(r0, c0)] = b0;
            *(short8*)&Bs[LDSOFF(r1, c1)] = b1;
        }
        __syncthreads();
        short8 af[4], bfr[4];
        const int q = l >> 4;
        #pragma unroll
        for (int mt = 0; mt < 4; mt++) {
            int rr = wm * 64 + mt * 16 + (l & 15);
            af[mt] = *(const short8*)&As[LDSOFF(rr, q)];
        }
        #pragma unroll
        for (int nt = 0; nt < 4; nt++) {
            int rr = wn * 64 + nt * 16 + (l & 15);
            bfr[nt] = *(const short8*)&Bs[LDSOFF(rr, q)];
        }
        #pragma unroll
        for (int mt = 0; mt < 4; mt++)
            #pragma unroll
            for (int nt = 0; nt < 4; nt++)
                acc[mt][nt] = __builtin_amdgcn_mfma_f32_16x16x32_bf16(
                    af[mt], bfr[nt], acc[mt][nt], 0, 0, 0);
    }
    // epilogue: C/D layout col = lane&15 (n), row = (lane>>4)*4 + reg (m)
    #pragma unroll
    for (int nt = 0; nt < 4; nt++) {
        int n = tn * 128 + wn * 64 + nt * 16 + (l & 15);
        float bn = bv[n];
        #pragma unroll
        for (int mt = 0; mt < 4; mt++) {
            #pragma unroll
            for (int rr = 0; rr < 4; rr++) {
                int m = tm * 128 + wm * 64 + mt * 16 + (l >> 4) * 4 + rr;
                C[(size_t)m * 1024 + n] = f2bf(acc[mt][nt][rr] + bn);
            }
        }
    }
}

// ---------------------------------------------------------------------------
// P2: recurrence. grid (64 batch, 2 dir) x 256 threads.
__device__ __forceinline__ int time_idx(int s, int len, int d) {
    int sc = (s < len - 1) ? s : (len - 1);
    return (d == 0) ? sc : (len - 1 - sc);
}

__global__ __attribute__((amdgpu_waves_per_eu(1, 2)))
__launch_bounds__(256, 1) void k_rec(const ushort_t* __restrict__ xproj,
                                     const int* __restrict__ wq4,
                                     const float* __restrict__ fscale4,
                                     const int* __restrict__ lens,
                                     float* __restrict__ out) {
    const int b = blockIdx.x, d = blockIdx.y;
    const int j = threadIdx.x;
    int len = lens[b];
    if (len < 1) len = 1;
    if (len > 512) len = 512;
    const ushort_t* xp = xproj + ((size_t)d * 64 + b) * 524288;  // 512*1024
    const int* wq = wq4 + d * 65536;
    float4 fr = *(const float4*)&fscale4[d * 1024 + j * 4];  // i,f,g,o

    // 256 dwords of int8 weights, pinned into VGPRs: the volatile asm ties
    // execute exactly once (cannot be duplicated/sunk into the time loop)
    // and their results are not rematerializable -> values stay register-
    // resident across all timesteps.
    int w0[64], w1[64], w2[64], w3[64];
    #pragma unroll
    for (int kc = 0; kc < 64; kc++) {
        int4 v = *(const int4*)&wq[kc * 1024 + j * 4];
        w0[kc] = v.x; w1[kc] = v.y; w2[kc] = v.z; w3[kc] = v.w;
    }
    #pragma unroll
    for (int kc = 0; kc < 64; kc++) {
        asm volatile("" : "+v"(w0[kc]), "+v"(w1[kc]), "+v"(w2[kc]), "+v"(w3[kc]));
    }

    __shared__ int h8[2][64] __attribute__((aligned(16)));
    if (j < 64) { h8[0][j] = 0; }

    // zero-fill this direction's half for t in [len, 512)
    {
        float4 z = {0.f, 0.f, 0.f, 0.f};
        int total4 = (512 - len) * 64;
        for (int i = j; i < total4; i += 256) {
            int t = len + (i >> 6);
            int c4 = i & 63;
            *(float4*)&out[((size_t)b * 512 + t) * 512 + d * 256 + c4 * 4] = z;
        }
    }
    __syncthreads();

    float c_state = 0.0f;
    uint2 xv0 = *(const uint2*)&xp[(size_t)time_idx(0, len, d) * 1024 + j * 4];
    uint2 xv1 = *(const uint2*)&xp[(size_t)time_idx(1, len, d) * 1024 + j * 4];

    for (int s = 0; s < len; s++) {
        uint2 xc = xv0;
        xv0 = xv1;
        uint2 xn = *(const uint2*)&xp[(size_t)time_idx(s + 2, len, d) * 1024 + j * 4];

        const int4* hb = (const int4*)&h8[s & 1][0];
        int a0 = 0, c0 = 0, a1 = 0, c1 = 0, a2 = 0, c2 = 0, a3 = 0, c3 = 0;
        #pragma unroll
        for (int kc = 0; kc < 16; kc++) {
            int4 hv = hb[kc];   // wave-uniform -> LDS broadcast
            a0 = dot4(w0[kc * 4 + 0], hv.x, a0); c0 = dot4(w0[kc * 4 + 1], hv.y, c0);
            a0 = dot4(w0[kc * 4 + 2], hv.z, a0); c0 = dot4(w0[kc * 4 + 3], hv.w, c0);
            a1 = dot4(w1[kc * 4 + 0], hv.x, a1); c1 = dot4(w1[kc * 4 + 1], hv.y, c1);
            a1 = dot4(w1[kc * 4 + 2], hv.z, a1); c1 = dot4(w1[kc * 4 + 3], hv.w, c1);
            a2 = dot4(w2[kc * 4 + 0], hv.x, a2); c2 = dot4(w2[kc * 4 + 1], hv.y, c2);
            a2 = dot4(w2[kc * 4 + 2], hv.z, a2); c2 = dot4(w2[kc * 4 + 3], hv.w, c2);
            a3 = dot4(w3[kc * 4 + 0], hv.x, a3); c3 = dot4(w3[kc * 4 + 1], hv.y, c3);
            a3 = dot4(w3[kc * 4 + 2], hv.z, a3); c3 = dot4(w3[kc * 4 + 3], hv.w, c3);
        }
        float pi = bf2f((ushort_t)(xc.x & 0xffffu)) + fr.x * (float)(a0 + c0);
        float pf = bf2f((ushort_t)(xc.x >> 16))     + fr.y * (float)(a1 + c1);
        float pg = bf2f((ushort_t)(xc.y & 0xffffu)) + fr.z * (float)(a2 + c2);
        float po = bf2f((ushort_t)(xc.y >> 16))     + fr.w * (float)(a3 + c3);

        float ig = fsig(pi), fg = fsig(pf), gg = ftanh(pg), og = fsig(po);
        c_state = fg * c_state + ig * gg;
        float h = og * ftanh(c_state);

        int t = time_idx(s, len, d);
        out[((size_t)b * 512 + t) * 512 + d * 256 + j] = h;

        int q = __float2int_rn(h * 127.0f);
        q = min(127, max(-127, q));
        ((char*)&h8[1 - (s & 1)][0])[j] = (char)q;

        xv1 = xn;
        lds_barrier();  // lgkm-only: global stores/prefetches stay in flight
    }
}

// ---------------------------------------------------------------------------
extern "C" void kernel_launch(void* const* d_in, const int* in_sizes, int n_in,
                              void* d_out, int out_size, void* d_ws, size_t ws_size,
                              hipStream_t stream) {
    (void)in_sizes; (void)n_in; (void)out_size;
    const float* x    = (const float*)d_in[0];
    const int*   lens = (const int*)d_in[1];
    const float* wihf = (const float*)d_in[2];
    const float* whhf = (const float*)d_in[3];
    const float* bihf = (const float*)d_in[4];
    const float* bhhf = (const float*)d_in[5];
    const float* wihb = (const float*)d_in[6];
    const float* whhb = (const float*)d_in[7];
    const float* bihb = (const float*)d_in[8];
    const float* bhhb = (const float*)d_in[9];
    float* out = (float*)d_out;

    char* ws = (char*)d_ws;
    ushort_t* xbf    = (ushort_t*)(ws + 0);          //  16,777,216 B
    ushort_t* wihbf  = (ushort_t*)(ws + 16777216);   //   1,048,576 B
    float*    biasv  = (float*)(ws + 17825792);      //       8,192 B
    int*      wq4    = (int*)(ws + 17833984);        //     524,288 B
    float*    fscale4= (float*)(ws + 18358272);      //       8,192 B
    ushort_t* xproj  = (ushort_t*)(ws + 18366464);   // 134,217,728 B
    const size_t REQ = 18366464 + 134217728ull;
    if (ws_size < REQ) {
        fprintf(stderr, "kernel_launch: ws too small: %zu < %zu\n", ws_size, REQ);
    }

    k_f2bf<<<8192, 256, 0, stream>>>(x, xbf, 8388608);
    k_wih<<<dim3(256, 2), 256, 0, stream>>>(wihf, wihb, wihbf);
    k_bias<<<8, 256, 0, stream>>>(bihf, bhhf, bihb, bhhb, biasv);
    k_quant<<<512, 256, 0, stream>>>(whhf, whhb, wq4, fscale4);
    k_gemm<<<dim3(8, 256, 2), 256, 0, stream>>>(xbf, wihbf, biasv, xproj);
    k_rec<<<dim3(64, 2), 256, 0, stream>>>(xproj, wq4, fscale4, lens, out);
}

// Round 5
// 638.506 us; speedup vs baseline: 1.4981x; 1.3474x over previous
//
#include <hip/hip_runtime.h>
#include <cstdio>

// ---------------------------------------------------------------------------
// BiLSTM  B=64, T=512, D=256, H=256
//   P0: x -> bf16; Wih -> bf16 with gate-permuted rows (n -> (n&255)*4+(n>>8));
//       permuted bias vectors; Whh -> int8 wq4[d][kc][j][gate]
//   P1: MFMA bf16 GEMM (contiguous epilogue) -> xproj[d][b*512+t][j*4+gate]
//   P2: recurrence: 128 WGs (64 batch x 2 dir) x 512 thr. Thread (p,j)
//       (p=tid>>8, j=tid&255) owns gate rows {2p,2p+1} of unit j: 128 pinned
//       int8-packed dwords -- fits under the v0..v255 VALU-addressable
//       ceiling (256/thread was architecturally impossible; that was the
//       R1-R4 stall). h int8 in double-buffered LDS; lgkm-only barriers.
// ---------------------------------------------------------------------------

typedef unsigned short ushort_t;
typedef __attribute__((ext_vector_type(8))) short short8;
typedef __attribute__((ext_vector_type(4))) float f32x4;

__device__ __forceinline__ ushort_t f2bf(float f) {
    union { float f; unsigned u; } v; v.f = f;
    unsigned r = v.u + 0x7fffu + ((v.u >> 16) & 1u);
    return (ushort_t)(r >> 16);
}
__device__ __forceinline__ float bf2f(ushort_t h) {
    union { unsigned u; float f; } v; v.u = ((unsigned)h) << 16;
    return v.f;
}

__device__ __forceinline__ float fexp2(float x) {
#if __has_builtin(__builtin_amdgcn_exp2f)
    return __builtin_amdgcn_exp2f(x);
#else
    return exp2f(x);
#endif
}
__device__ __forceinline__ float frcp(float x) {
#if __has_builtin(__builtin_amdgcn_rcpf)
    return __builtin_amdgcn_rcpf(x);
#else
    return 1.0f / x;
#endif
}
__device__ __forceinline__ float fsig(float x) {
    return frcp(1.0f + fexp2(-1.44269504089f * x));
}
__device__ __forceinline__ float ftanh(float x) {
    float e = fexp2(2.88539008178f * x);
    return 1.0f - 2.0f * frcp(e + 1.0f);
}

__device__ __forceinline__ int dot4(int a, int b, int c) {
#if __has_builtin(__builtin_amdgcn_sdot4)
    return __builtin_amdgcn_sdot4(a, b, c, false);
#else
    int r = c;
    r += ((a << 24) >> 24) * ((b << 24) >> 24);
    r += ((a << 16) >> 24) * ((b << 16) >> 24);
    r += ((a << 8) >> 24) * ((b << 8) >> 24);
    r += (a >> 24) * (b >> 24);
    return r;
#endif
}

// LDS-only barrier: drain lgkm (LDS ops) but NOT vmcnt.
__device__ __forceinline__ void lds_barrier() {
    asm volatile("s_waitcnt lgkmcnt(0)\n\ts_barrier" ::: "memory");
}

// ---------------------------------------------------------------------------
// P0a: fp32 -> bf16 (n multiple of 4)
__global__ __launch_bounds__(256) void k_f2bf(const float* __restrict__ in,
                                              ushort_t* __restrict__ out, int n) {
    int i = (blockIdx.x * 256 + threadIdx.x) * 4;
    if (i + 3 < n) {
        float4 v = *(const float4*)&in[i];
        ushort4 o;
        o.x = f2bf(v.x); o.y = f2bf(v.y); o.z = f2bf(v.z); o.w = f2bf(v.w);
        *(ushort4*)&out[i] = o;
    }
}

// P0b: Wih fp32 -> bf16 with gate-permuted ROW order:
//   dst[d][(n&255)*4 + (n>>8)][k] = src_d[n][k]
__global__ __launch_bounds__(256) void k_wih(const float* __restrict__ wihf,
                                             const float* __restrict__ wihb,
                                             ushort_t* __restrict__ dst) {
    int d = blockIdx.y;
    int n = blockIdx.x * 4 + (threadIdx.x >> 6);   // 0..1023
    int l = threadIdx.x & 63;
    const float* src = (d ? wihb : wihf) + (size_t)n * 256;
    float4 v = *(const float4*)&src[l * 4];
    int np = (n & 255) * 4 + (n >> 8);
    ushort4 o;
    o.x = f2bf(v.x); o.y = f2bf(v.y); o.z = f2bf(v.z); o.w = f2bf(v.w);
    *(ushort4*)&dst[((size_t)d * 1024 + np) * 256 + l * 4] = o;
}

// P0c: permuted bias vectors bv[d][(n&255)*4 + (n>>8)] = bih_d[n] + bhh_d[n]
__global__ __launch_bounds__(256) void k_bias(const float* __restrict__ bihf,
                                              const float* __restrict__ bhhf,
                                              const float* __restrict__ bihb,
                                              const float* __restrict__ bhhb,
                                              float* __restrict__ bv) {
    int i = blockIdx.x * 256 + threadIdx.x;   // 0..2047
    int d = i >> 10, n = i & 1023;
    float s = d ? (bihb[n] + bhhb[n]) : (bihf[n] + bhhf[n]);
    bv[d * 1024 + (n & 255) * 4 + (n >> 8)] = s;
}

// P0d: quantize Whh rows to int8.
// wq4[d*65536 + kc*1024 + j*4 + gate], kc=k/4, j=row&255, gate=row>>8.
__global__ __launch_bounds__(256) void k_quant(const float* __restrict__ whhf,
                                               const float* __restrict__ whhb,
                                               int* __restrict__ wq4,
                                               float* __restrict__ fscale4) {
    int rowg = blockIdx.x * 4 + (threadIdx.x >> 6);   // 0..2047
    int l = threadIdx.x & 63;                          // = kc
    int d = rowg >> 10;
    int row = rowg & 1023;
    const float* W = (d ? whhb : whhf) + (size_t)row * 256;
    float4 v = *(const float4*)&W[l * 4];
    float m = fmaxf(fmaxf(fabsf(v.x), fabsf(v.y)), fmaxf(fabsf(v.z), fabsf(v.w)));
    #pragma unroll
    for (int off = 32; off > 0; off >>= 1) m = fmaxf(m, __shfl_xor(m, off));
    float inv = (m > 0.0f) ? (127.0f / m) : 0.0f;
    int q0 = __float2int_rn(v.x * inv);
    int q1 = __float2int_rn(v.y * inv);
    int q2 = __float2int_rn(v.z * inv);
    int q3 = __float2int_rn(v.w * inv);
    q0 = min(127, max(-127, q0)); q1 = min(127, max(-127, q1));
    q2 = min(127, max(-127, q2)); q3 = min(127, max(-127, q3));
    int packed = (q0 & 255) | ((q1 & 255) << 8) | ((q2 & 255) << 16) | ((q3 & 255) << 24);
    int j = row & 255, gate = row >> 8;
    wq4[d * 65536 + l * 1024 + j * 4 + gate] = packed;
    if (l == 0) fscale4[d * 1024 + j * 4 + gate] = m / (127.0f * 127.0f);
}

// ---------------------------------------------------------------------------
// P1: bf16 GEMM (contiguous epilogue; B rows pre-permuted).
#define LDSOFF(r, kc) ((r) * 32 + ((((kc) + ((r) >> 1)) & 3) * 8))

__global__ __launch_bounds__(256) void k_gemm(const ushort_t* __restrict__ A,
                                              const ushort_t* __restrict__ Bw,
                                              const float* __restrict__ biasv,
                                              ushort_t* __restrict__ Xp) {
    const int dir = blockIdx.z;
    const ushort_t* Bmat = Bw + dir * 262144;
    const float* bv = biasv + dir * 1024;
    ushort_t* C = Xp + (size_t)dir * 33554432;
    const int tn = blockIdx.x;   // 0..7
    const int tm = blockIdx.y;   // 0..255
    const int tid = threadIdx.x;
    const int w = tid >> 6, l = tid & 63;
    const int wm = w & 1, wn = w >> 1;

    __shared__ ushort_t As[128 * 32];
    __shared__ ushort_t Bs[128 * 32];

    f32x4 acc[4][4];
    #pragma unroll
    for (int i = 0; i < 4; i++)
        #pragma unroll
        for (int jj = 0; jj < 4; jj++) acc[i][jj] = (f32x4){0.f, 0.f, 0.f, 0.f};

    const int r0 = tid >> 2, c0 = tid & 3;
    const int r1 = (tid + 256) >> 2, c1 = tid & 3;

    for (int kb = 0; kb < 8; kb++) {
        __syncthreads();
        {
            short8 a0 = *(const short8*)&A[((size_t)(tm * 128 + r0)) * 256 + kb * 32 + c0 * 8];
            short8 a1 = *(const short8*)&A[((size_t)(tm * 128 + r1)) * 256 + kb * 32 + c1 * 8];
            short8 b0 = *(const short8*)&Bmat[((size_t)(tn * 128 + r0)) * 256 + kb * 32 + c0 * 8];
            short8 b1 = *(const short8*)&Bmat[((size_t)(tn * 128 + r1)) * 256 + kb * 32 + c1 * 8];
            *(short8*)&As[LDSOFF(r0, c0)] = a0;
            *(short8*)&As[LDSOFF(r1, c1)] = a1;
            *(short8*)&Bs[LDSOFF(r0, c0)] = b0;
            *(short8*)&Bs[LDSOFF(r1, c1)] = b1;
        }
        __syncthreads();
        short8 af[4], bfr[4];
        const int q = l >> 4;
        #pragma unroll
        for (int mt = 0; mt < 4; mt++) {
            int rr = wm * 64 + mt * 16 + (l & 15);
            af[mt] = *(const short8*)&As[LDSOFF(rr, q)];
        }
        #pragma unroll
        for (int nt = 0; nt < 4; nt++) {
            int rr = wn * 64 + nt * 16 + (l & 15);
            bfr[nt] = *(const short8*)&Bs[LDSOFF(rr, q)];
        }
        #pragma unroll
        for (int mt = 0; mt < 4; mt++)
            #pragma unroll
            for (int nt = 0; nt < 4; nt++)
                acc[mt][nt] = __builtin_amdgcn_mfma_f32_16x16x32_bf16(
                    af[mt], bfr[nt], acc[mt][nt], 0, 0, 0);
    }
    #pragma unroll
    for (int nt = 0; nt < 4; nt++) {
        int n = tn * 128 + wn * 64 + nt * 16 + (l & 15);
        float bn = bv[n];
        #pragma unroll
        for (int mt = 0; mt < 4; mt++) {
            #pragma unroll
            for (int rr = 0; rr < 4; rr++) {
                int m = tm * 128 + wm * 64 + mt * 16 + (l >> 4) * 4 + rr;
                C[(size_t)m * 1024 + n] = f2bf(acc[mt][nt][rr] + bn);
            }
        }
    }
}

// ---------------------------------------------------------------------------
// P2: recurrence. grid (64 batch, 2 dir) x 512 threads.
// Thread (p = tid>>8, j = tid&255) owns gate rows {2p, 2p+1} of unit j.
// p=0 -> gates i,f (and owns c[j], h[j]); p=1 -> gates g,o.
__device__ __forceinline__ int time_idx(int s, int len, int d) {
    int sc = (s < len - 1) ? s : (len - 1);
    return (d == 0) ? sc : (len - 1 - sc);
}

__global__ __launch_bounds__(512, 2) void k_rec(const ushort_t* __restrict__ xproj,
                                                const int* __restrict__ wq4,
                                                const float* __restrict__ fscale4,
                                                const int* __restrict__ lens,
                                                float* __restrict__ out) {
    const int b = blockIdx.x, d = blockIdx.y;
    const int tid = threadIdx.x;
    const int j = tid & 255, p = tid >> 8;
    int len = lens[b];
    if (len < 1) len = 1;
    if (len > 512) len = 512;
    const ushort_t* xp = xproj + ((size_t)d * 64 + b) * 524288;  // 512*1024
    const int* wq = wq4 + d * 65536;
    float2 fr = *(const float2*)&fscale4[d * 1024 + j * 4 + p * 2];

    // 128 dwords of int8 weights pinned into VGPRs. This fits under the
    // v0..v255 VALU-addressable ceiling (256 dwords/thread did not -- the
    // R1-R4 spill-grind). asm ties force once-only load + loop-long liveness.
    int wa[64], wb[64];
    #pragma unroll
    for (int kc = 0; kc < 64; kc++) {
        int2 v = *(const int2*)&wq[kc * 1024 + j * 4 + p * 2];
        wa[kc] = v.x; wb[kc] = v.y;
    }
    #pragma unroll
    for (int kc = 0; kc < 64; kc++) {
        asm volatile("" : "+v"(wa[kc]), "+v"(wb[kc]));
    }

    __shared__ int h8[2][64] __attribute__((aligned(16)));
    __shared__ float gA[256], oA[256];
    if (tid < 64) h8[0][tid] = 0;

    // zero-fill this direction's half for t in [len, 512)
    {
        float4 z = {0.f, 0.f, 0.f, 0.f};
        int total4 = (512 - len) * 64;
        for (int i = tid; i < total4; i += 512) {
            int t = len + (i >> 6);
            int c4 = i & 63;
            *(float4*)&out[((size_t)b * 512 + t) * 512 + d * 256 + c4 * 4] = z;
        }
    }
    __syncthreads();

    float c_state = 0.0f;
    unsigned xv0 = *(const unsigned*)&xp[(size_t)time_idx(0, len, d) * 1024 + j * 4 + p * 2];
    unsigned xv1 = *(const unsigned*)&xp[(size_t)time_idx(1, len, d) * 1024 + j * 4 + p * 2];

    for (int s = 0; s < len; s++) {
        unsigned xc = xv0;
        xv0 = xv1;
        unsigned xn = *(const unsigned*)&xp[(size_t)time_idx(s + 2, len, d) * 1024 + j * 4 + p * 2];

        const int4* hb = (const int4*)&h8[s & 1][0];
        int a0 = 0, c0 = 0, a1 = 0, c1 = 0;
        #pragma unroll
        for (int kc = 0; kc < 16; kc++) {
            int4 hv = hb[kc];   // wave-uniform -> LDS broadcast
            a0 = dot4(wa[kc * 4 + 0], hv.x, a0); c0 = dot4(wa[kc * 4 + 1], hv.y, c0);
            a0 = dot4(wa[kc * 4 + 2], hv.z, a0); c0 = dot4(wa[kc * 4 + 3], hv.w, c0);
            a1 = dot4(wb[kc * 4 + 0], hv.x, a1); c1 = dot4(wb[kc * 4 + 1], hv.y, c1);
            a1 = dot4(wb[kc * 4 + 2], hv.z, a1); c1 = dot4(wb[kc * 4 + 3], hv.w, c1);
        }
        float pre0 = bf2f((ushort_t)(xc & 0xffffu)) + fr.x * (float)(a0 + c0);
        float pre1 = bf2f((ushort_t)(xc >> 16))     + fr.y * (float)(a1 + c1);

        if (p) {                       // wave-uniform branch (waves 4..7)
            gA[j] = ftanh(pre0);       // gate g
            oA[j] = fsig(pre1);        // gate o
        }
        lds_barrier();
        if (!p) {                      // waves 0..3
            float ig = fsig(pre0), fg = fsig(pre1);
            c_state = fg * c_state + ig * gA[j];
            float h = oA[j] * ftanh(c_state);
            int t = time_idx(s, len, d);
            out[((size_t)b * 512 + t) * 512 + d * 256 + j] = h;
            int q = __float2int_rn(h * 127.0f);
            q = min(127, max(-127, q));
            ((char*)&h8[1 - (s & 1)][0])[j] = (char)q;
        }
        xv1 = xn;
        lds_barrier();
    }
}

// ---------------------------------------------------------------------------
extern "C" void kernel_launch(void* const* d_in, const int* in_sizes, int n_in,
                              void* d_out, int out_size, void* d_ws, size_t ws_size,
                              hipStream_t stream) {
    (void)in_sizes; (void)n_in; (void)out_size;
    const float* x    = (const float*)d_in[0];
    const int*   lens = (const int*)d_in[1];
    const float* wihf = (const float*)d_in[2];
    const float* whhf = (const float*)d_in[3];
    const float* bihf = (const float*)d_in[4];
    const float* bhhf = (const float*)d_in[5];
    const float* wihb = (const float*)d_in[6];
    const float* whhb = (const float*)d_in[7];
    const float* bihb = (const float*)d_in[8];
    const float* bhhb = (const float*)d_in[9];
    float* out = (float*)d_out;

    char* ws = (char*)d_ws;
    ushort_t* xbf    = (ushort_t*)(ws + 0);          //  16,777,216 B
    ushort_t* wihbf  = (ushort_t*)(ws + 16777216);   //   1,048,576 B
    float*    biasv  = (float*)(ws + 17825792);      //       8,192 B
    int*      wq4    = (int*)(ws + 17833984);        //     524,288 B
    float*    fscale4= (float*)(ws + 18358272);      //       8,192 B
    ushort_t* xproj  = (ushort_t*)(ws + 18366464);   // 134,217,728 B
    const size_t REQ = 18366464 + 134217728ull;
    if (ws_size < REQ) {
        fprintf(stderr, "kernel_launch: ws too small: %zu < %zu\n", ws_size, REQ);
    }

    k_f2bf<<<8192, 256, 0, stream>>>(x, xbf, 8388608);
    k_wih<<<dim3(256, 2), 256, 0, stream>>>(wihf, wihb, wihbf);
    k_bias<<<8, 256, 0, stream>>>(bihf, bhhf, bihb, bhhb, biasv);
    k_quant<<<512, 256, 0, stream>>>(whhf, whhb, wq4, fscale4);
    k_gemm<<<dim3(8, 256, 2), 256, 0, stream>>>(xbf, wihbf, biasv, xproj);
    k_rec<<<dim3(64, 2), 512, 0, stream>>>(xproj, wq4, fscale4, lens, out);
}